// Round 7
// baseline (161.711 us; speedup 1.0000x reference)
//
#include <hip/hip_runtime.h>

#define B_N 32
#define LQ  1024
#define LK  1024
#define DH  128

typedef __attribute__((ext_vector_type(4))) float    f32x4;
typedef __attribute__((ext_vector_type(8))) short    s16x8;
typedef __attribute__((ext_vector_type(4))) _Float16 f16x4;
typedef __attribute__((ext_vector_type(8))) _Float16 f16x8;

// fp32 -> bf16 round-to-nearest-even
__device__ inline unsigned short f2bf(float f) {
    union { float f; unsigned u; } c; c.f = f;
    unsigned u = c.u;
    u += 0x7fffu + ((u >> 16) & 1u);
    return (unsigned short)(u >> 16);
}

// logit2 = score * (1/sqrt(128)) * log2(e)
#define ESCALE 0.12751743f

// ---------------------------------------------------------------------------
// Prep, one kernel, no __syncthreads anywhere:
//  blocks 0..2047   : K cast fp32->bf16, SAME row-major layout (pure stream,
//                     perfectly coalesced; attn reads 16x16 A-frags straight
//                     from row-major — 16 fully-utilized 64B lines per frag).
//  blocks 2048..2559: V transpose -> Vt f16 fragment-pairs for PV (16x16x16).
//    One 16-row kpos-group per WAVE, wave-private LDS + lgkmcnt fence.
//    pair v=(b*64+kg)*4+dp: elem(lane,i)   = V[b][kg*16+(lane>>4)*4+i][dp*32+(lane&15)]
//                           elem(lane,4+i) = V[b][kg*16+(lane>>4)*4+i][dp*32+16+(lane&15)]
// ---------------------------------------------------------------------------
__global__ __launch_bounds__(256)
void prep_kv(const float* __restrict__ K, const float* __restrict__ V,
             unsigned short* __restrict__ Kc, _Float16* __restrict__ Vt)
{
    __shared__ float tl[4][16 * 132];
    const int tid  = threadIdx.x;
    const int lane = tid & 63;
    const int wv   = tid >> 6;

    if (blockIdx.x < 2048) {
        // ---- K cast: 8 contiguous floats per thread ----
        const size_t base = ((size_t)blockIdx.x * 256 + tid) * 8;
        const float4 a = *(const float4*)(K + base);
        const float4 c = *(const float4*)(K + base + 4);
        ushort4 lo, hi;
        lo.x = f2bf(a.x); lo.y = f2bf(a.y); lo.z = f2bf(a.z); lo.w = f2bf(a.w);
        hi.x = f2bf(c.x); hi.y = f2bf(c.y); hi.z = f2bf(c.z); hi.w = f2bf(c.w);
        *(ushort4*)(Kc + base)     = lo;
        *(ushort4*)(Kc + base + 4) = hi;
    } else {
        // ---- V transpose: one 16-row group per wave ----
        const int t  = (blockIdx.x - 2048) * 4 + wv;   // 2048 tasks
        const int b  = t >> 6, kg = t & 63;
        const int n    = lane & 15;
        const int quad = lane >> 4;
        float* my = tl[wv];

        const float4* src = (const float4*)(V + ((size_t)b * LK + kg * 16) * DH);
        #pragma unroll
        for (int h = 0; h < 8; ++h) {                  // 512 float4 = 16 rows
            const int idx = h * 64 + lane;
            const int row = idx >> 5, c4 = idx & 31;
            *(float4*)&my[row * 132 + c4 * 4] = src[idx];
        }
        __asm__ volatile("s_waitcnt lgkmcnt(0)" ::: "memory");  // wave-private

        #pragma unroll
        for (int dp = 0; dp < 4; ++dp) {
            f16x8 t8;
            #pragma unroll
            for (int i = 0; i < 4; ++i) {
                const float* row = &my[(quad * 4 + i) * 132 + dp * 32 + n];
                t8[i]     = (_Float16)row[0];
                t8[4 + i] = (_Float16)row[16];
            }
            const int v = (b * 64 + kg) * 4 + dp;
            *(f16x8*)(Vt + (size_t)v * 512 + lane * 8) = t8;
        }
    }
}

// ---------------------------------------------------------------------------
// Attention: M=32 q-rows per wave, 2-wave blocks, split-K (wave w: chunks
// w, w+2, ...) — fixed-max softmax makes partials additive, merged once via
// 16 KB LDS + one __syncthreads. Loop body is register-only; K/V fragments
// streamed per g-tile (live set ~190 VGPR — the r6 spill is the failure
// mode this layout avoids).
// Transposed-S trick: S^T = K·Q^T C-layout (row=kpos=quad*4+r, col=qrow)
// == A-operand layout of 16x16x16 f16 MFMA -> exp2(S^T) feeds PV directly.
// ---------------------------------------------------------------------------
__global__ __launch_bounds__(128, 2)
void attn_fwd(const float* __restrict__ Q, const unsigned short* __restrict__ Kc,
              const _Float16* __restrict__ Vt, const int* __restrict__ VL,
              float* __restrict__ O)
{
    __shared__ f32x4 Om[2][8][64];
    __shared__ float Lm[2][64];

    const int tid  = threadIdx.x;
    const int lane = tid & 63;
    const int wv   = tid >> 6;
    const int quad = lane >> 4;
    const int m16  = lane & 15;

    // blockIdx = qg*32 + b: batch->XCD round-robin; 4 batches/XCD -> ~2 MB
    // of Kc+Vt per XCD (L2-resident).
    const int b  = blockIdx.x & 31;
    const int qg = blockIdx.x >> 5;
    const int q0 = qg * 32;

    const int vl = VL[b];
    const int nch = (vl > 0) ? ((vl + 63) >> 6) : 16;
    const float emaskval = (vl == 0) ? 1.0f : 0.0f;

    // Q fragments for 2 qrow-tiles (B-operand of transposed QK^T)
    s16x8 qf[2][4];
    #pragma unroll
    for (int h = 0; h < 2; ++h) {
        const float* qrow = Q + ((size_t)b * LQ + q0 + h * 16 + m16) * DH + quad * 8;
        #pragma unroll
        for (int s = 0; s < 4; ++s) {
            const float4 a = *(const float4*)(qrow + s * 32);
            const float4 c = *(const float4*)(qrow + s * 32 + 4);
            union { s16x8 v; unsigned short u[8]; } t;
            t.u[0] = f2bf(a.x); t.u[1] = f2bf(a.y); t.u[2] = f2bf(a.z); t.u[3] = f2bf(a.w);
            t.u[4] = f2bf(c.x); t.u[5] = f2bf(c.y); t.u[6] = f2bf(c.z); t.u[7] = f2bf(c.w);
            qf[h][s] = t.v;
        }
    }

    f32x4 o[2][8];
    #pragma unroll
    for (int h = 0; h < 2; ++h)
        #pragma unroll
        for (int dt = 0; dt < 8; ++dt) o[h][dt] = (f32x4){0.f, 0.f, 0.f, 0.f};
    float lrun[2] = {0.f, 0.f};

    // K row-major bf16: lane reads 16 B of row (q0-independent)
    const unsigned short* krow = Kc + ((size_t)b * LK + m16) * DH + quad * 8;
    const _Float16*       vbase = Vt + (size_t)b * (256 * 512) + lane * 8;

    for (int kb = wv; kb < nch; kb += 2) {
        const bool maskc = (kb * 64 + 64 > vl);
        f16x4 pA[2][4];

        // ---- S^T = K Q^T per 16-kpos tile g, softmaxed immediately ----
        #pragma unroll
        for (int g = 0; g < 4; ++g) {
            const unsigned short* kr = krow + (size_t)(kb * 64 + g * 16) * DH;
            f32x4 st0 = (f32x4){0.f, 0.f, 0.f, 0.f};
            f32x4 st1 = (f32x4){0.f, 0.f, 0.f, 0.f};
            #pragma unroll
            for (int s = 0; s < 4; ++s) {
                const s16x8 kf = *(const s16x8*)(kr + s * 32);
                st0 = __builtin_amdgcn_mfma_f32_16x16x32_bf16(kf, qf[0][s], st0, 0, 0, 0);
                st1 = __builtin_amdgcn_mfma_f32_16x16x32_bf16(kf, qf[1][s], st1, 0, 0, 0);
            }
            #pragma unroll
            for (int i = 0; i < 4; ++i) {
                float e0 = __builtin_amdgcn_exp2f(st0[i] * ESCALE);
                float e1 = __builtin_amdgcn_exp2f(st1[i] * ESCALE);
                if (maskc && (kb * 64 + g * 16 + quad * 4 + i >= vl)) { e0 = emaskval; e1 = emaskval; }
                lrun[0] += e0; lrun[1] += e1;
                pA[0][g][i] = (_Float16)e0;
                pA[1][g][i] = (_Float16)e1;
            }
        }

        // ---- O += P V : 4 kpos-tiles x 4 d-pairs ----
        #pragma unroll
        for (int g = 0; g < 4; ++g) {
            const _Float16* vc = vbase + (size_t)((kb * 4 + g) * 4) * 512;
            #pragma unroll
            for (int dp = 0; dp < 4; ++dp) {
                const f16x8 w  = *(const f16x8*)(vc + dp * 512);
                const f16x4 lo = __builtin_shufflevector(w, w, 0, 1, 2, 3);
                const f16x4 hi = __builtin_shufflevector(w, w, 4, 5, 6, 7);
                o[0][dp * 2]     = __builtin_amdgcn_mfma_f32_16x16x16f16(pA[0][g], lo, o[0][dp * 2],     0, 0, 0);
                o[0][dp * 2 + 1] = __builtin_amdgcn_mfma_f32_16x16x16f16(pA[0][g], hi, o[0][dp * 2 + 1], 0, 0, 0);
                o[1][dp * 2]     = __builtin_amdgcn_mfma_f32_16x16x16f16(pA[1][g], lo, o[1][dp * 2],     0, 0, 0);
                o[1][dp * 2 + 1] = __builtin_amdgcn_mfma_f32_16x16x16f16(pA[1][g], hi, o[1][dp * 2 + 1], 0, 0, 0);
            }
        }
    }

    // ---- split-K merge: wave w exports its OTHER half, keeps h = wv ----
    const int oh = 1 - wv;
    #pragma unroll
    for (int dt = 0; dt < 8; ++dt) Om[wv][dt][lane] = o[oh][dt];
    Lm[wv][lane] = lrun[oh];
    __syncthreads();
    f32x4 om[8];
    #pragma unroll
    for (int dt = 0; dt < 8; ++dt) om[dt] = o[wv][dt] + Om[oh][dt][lane];
    float L = lrun[wv] + Lm[oh][lane];

    // L[qrow=m16] total across quads, then per-row 1/L via shfl
    L += __shfl_xor(L, 16);
    L += __shfl_xor(L, 32);
    const size_t obase = ((size_t)b * LQ + q0 + wv * 16 + quad * 4) * DH + m16;
    #pragma unroll
    for (int r = 0; r < 4; ++r) {
        const float inv = 1.0f / __shfl(L, quad * 4 + r);
        #pragma unroll
        for (int dt = 0; dt < 8; ++dt)
            O[obase + (size_t)r * DH + dt * 16] = om[dt][r] * inv;
    }
}

extern "C" void kernel_launch(void* const* d_in, const int* in_sizes, int n_in,
                              void* d_out, int out_size, void* d_ws, size_t ws_size,
                              hipStream_t stream) {
    const float* Q  = (const float*)d_in[0];
    const float* K  = (const float*)d_in[1];
    const float* V  = (const float*)d_in[2];
    const int*   VL = (const int*)d_in[3];
    float* O = (float*)d_out;
    (void)in_sizes; (void)n_in; (void)out_size; (void)ws_size;

    unsigned short* Kc = (unsigned short*)d_ws;                      // 8 MB row-major bf16 K
    _Float16*       Vt = (_Float16*)(Kc + (size_t)B_N * LK * DH);    // 8 MB V frag-pairs

    prep_kv<<<dim3(2560), dim3(256), 0, stream>>>(K, V, Kc, Vt);
    attn_fwd<<<dim3(B_N * (LQ / 32)), dim3(128), 0, stream>>>(Q, Kc, Vt, VL, O);
}

// Round 8
// 135.149 us; speedup vs baseline: 1.1965x; 1.1965x over previous
//
#include <hip/hip_runtime.h>

#define B_N 32
#define LQ  1024
#define LK  1024
#define DH  128

typedef __attribute__((ext_vector_type(4))) float    f32x4;
typedef __attribute__((ext_vector_type(8))) short    s16x8;
typedef __attribute__((ext_vector_type(4))) _Float16 f16x4;
typedef __attribute__((ext_vector_type(8))) _Float16 f16x8;

// fp32 -> bf16 round-to-nearest-even
__device__ inline unsigned short f2bf(float f) {
    union { float f; unsigned u; } c; c.f = f;
    unsigned u = c.u;
    u += 0x7fffu + ((u >> 16) & 1u);
    return (unsigned short)(u >> 16);
}

// logit2 = score * (1/sqrt(128)) * log2(e)
#define ESCALE 0.12751743f

// ---------------------------------------------------------------------------
// Prepass (r5 layout, fully coalesced via LDS tile transpose).
// blocks 0..1023: K tiles -> Kb bf16 fragments for QK^T (16x16x32):
//   frag w=b*256+tt*4+s: elem(lane,j) = K[b][tt*16+(lane&15)][s*32+(lane>>4)*8+j]
// blocks 1024..2047: V tiles -> Vt f16 fragment-PAIRS for PV (16x16x16):
//   pair v=(b*64+kg)*4+dp: elem(lane,i)   = V[b][kg*16+(lane>>4)*4+i][(2dp  )*16+(lane&15)]
//                          elem(lane,4+i) = V[b][kg*16+(lane>>4)*4+i][(2dp+1)*16+(lane&15)]
// Both lane-linear 16 B/lane -> attn loads one dwordx4 per lane per frag.
// ---------------------------------------------------------------------------
__global__ __launch_bounds__(256)
void prep_kv(const float* __restrict__ K, const float* __restrict__ V,
             unsigned short* __restrict__ Kb, _Float16* __restrict__ Vt)
{
    __shared__ float tl[32 * 132];
    const int tid  = threadIdx.x;
    const int lane = tid & 63;
    const int wv   = tid >> 6;
    const int n    = lane & 15;
    const int quad = lane >> 4;

    const bool isK = blockIdx.x < 1024;
    const int  t   = isK ? blockIdx.x : (blockIdx.x - 1024);
    const int  b   = t >> 5, kt = t & 31;

    const float4* src = (const float4*)((isK ? K : V) + ((size_t)b * LK + kt * 32) * DH);
    #pragma unroll
    for (int h = 0; h < 4; ++h) {
        const int idx = h * 256 + tid;
        const int row = idx >> 5, c4 = idx & 31;
        *(float4*)&tl[row * 132 + c4 * 4] = src[idx];
    }
    __syncthreads();

    if (isK) {
        union { s16x8 v; unsigned short u[8]; } t8;
        #pragma unroll
        for (int h = 0; h < 2; ++h) {
            const int f = wv * 2 + h;
            const int tt2 = f >> 2, s = f & 3;
            const float* p = &tl[(tt2 * 16 + n) * 132 + s * 32 + quad * 8];
            const float4 a = *(const float4*)p;
            const float4 c = *(const float4*)(p + 4);
            t8.u[0] = f2bf(a.x); t8.u[1] = f2bf(a.y); t8.u[2] = f2bf(a.z); t8.u[3] = f2bf(a.w);
            t8.u[4] = f2bf(c.x); t8.u[5] = f2bf(c.y); t8.u[6] = f2bf(c.z); t8.u[7] = f2bf(c.w);
            const int w = b * 256 + (kt * 2 + tt2) * 4 + s;
            *(s16x8*)(Kb + (size_t)w * 512 + lane * 8) = t8.v;
        }
    } else {
        #pragma unroll
        for (int h = 0; h < 2; ++h) {
            const int f  = wv * 2 + h;
            const int kg = f >> 2, dp = f & 3;
            f16x8 t8;
            #pragma unroll
            for (int i = 0; i < 4; ++i) {
                const float* row = &tl[(kg * 16 + quad * 4 + i) * 132 + dp * 32 + n];
                t8[i]     = (_Float16)row[0];
                t8[4 + i] = (_Float16)row[16];
            }
            const int v = (b * 64 + kt * 2 + kg) * 4 + dp;
            *(f16x8*)(Vt + (size_t)v * 512 + lane * 8) = t8;
        }
    }
}

// ---------------------------------------------------------------------------
// Attention: M=32 q-rows per wave, 2-wave blocks, split-K (wave w: chunks
// w, w+2, ...); fixed-max softmax makes partials additive -> one 16 KB LDS
// merge + one __syncthreads at the end. Loop body register-only.
// amdgpu_waves_per_eu(2,2) PINS 2 waves/EU -> 256-VGPR budget: the r6/r7
// failure was the allocator targeting high occupancy (92 regs) and spilling
// the M=32 accumulators to scratch (WRITE_SIZE 81-100 MB). 1024 blocks x 2
// waves = 4 blocks/CU matches the pin exactly.
// Transposed-S trick: S^T = K·Q^T C-layout (row=kpos=quad*4+i, col=qrow)
// == A-operand layout of 16x16x16 f16 MFMA -> exp2(S^T) feeds PV directly.
// ---------------------------------------------------------------------------
__global__ __launch_bounds__(128)
__attribute__((amdgpu_waves_per_eu(2, 2)))
void attn_fwd(const float* __restrict__ Q, const unsigned short* __restrict__ Kb,
              const _Float16* __restrict__ Vt, const int* __restrict__ VL,
              float* __restrict__ O)
{
    __shared__ f32x4 Om[2][8][64];
    __shared__ float Lm[2][64];

    const int tid  = threadIdx.x;
    const int lane = tid & 63;
    const int wv   = tid >> 6;
    const int quad = lane >> 4;
    const int m16  = lane & 15;

    // blockIdx = qg*32 + b: batch->XCD round-robin; ~2 MB Kb+Vt per XCD (L2).
    const int b  = blockIdx.x & 31;
    const int qg = blockIdx.x >> 5;
    const int q0 = qg * 32;

    const int vl = VL[b];
    const int nch = (vl > 0) ? ((vl + 63) >> 6) : 16;
    const float emaskval = (vl == 0) ? 1.0f : 0.0f;

    // Q fragments for 2 qrow-tiles (B-operand of transposed QK^T)
    s16x8 qf[2][4];
    #pragma unroll
    for (int h = 0; h < 2; ++h) {
        const float* qrow = Q + ((size_t)b * LQ + q0 + h * 16 + m16) * DH + quad * 8;
        #pragma unroll
        for (int s = 0; s < 4; ++s) {
            const float4 a = *(const float4*)(qrow + s * 32);
            const float4 c = *(const float4*)(qrow + s * 32 + 4);
            union { s16x8 v; unsigned short u[8]; } t;
            t.u[0] = f2bf(a.x); t.u[1] = f2bf(a.y); t.u[2] = f2bf(a.z); t.u[3] = f2bf(a.w);
            t.u[4] = f2bf(c.x); t.u[5] = f2bf(c.y); t.u[6] = f2bf(c.z); t.u[7] = f2bf(c.w);
            qf[h][s] = t.v;
        }
    }

    f32x4 o[2][8];
    #pragma unroll
    for (int h = 0; h < 2; ++h)
        #pragma unroll
        for (int dt = 0; dt < 8; ++dt) o[h][dt] = (f32x4){0.f, 0.f, 0.f, 0.f};
    float lrun[2] = {0.f, 0.f};

    const unsigned short* kbase = Kb + (size_t)b * (256 * 512) + lane * 8;
    const _Float16*       vbase = Vt + (size_t)b * (256 * 512) + lane * 8;

    for (int kb = wv; kb < nch; kb += 2) {
        const bool maskc = (kb * 64 + 64 > vl);
        f16x4 pA[2][4];

        // ---- S^T = K Q^T per 16-kpos tile g, softmaxed immediately.
        // g-loop fully unrolled; with the 256-reg budget the compiler can
        // hoist all 16 lane-linear K-frag loads ahead of the MFMAs itself.
        #pragma unroll
        for (int g = 0; g < 4; ++g) {
            const unsigned short* kc = kbase + (size_t)((kb * 4 + g) * 4) * 512;
            f32x4 st0 = (f32x4){0.f, 0.f, 0.f, 0.f};
            f32x4 st1 = (f32x4){0.f, 0.f, 0.f, 0.f};
            #pragma unroll
            for (int s = 0; s < 4; ++s) {
                const s16x8 kf = *(const s16x8*)(kc + s * 512);
                st0 = __builtin_amdgcn_mfma_f32_16x16x32_bf16(kf, qf[0][s], st0, 0, 0, 0);
                st1 = __builtin_amdgcn_mfma_f32_16x16x32_bf16(kf, qf[1][s], st1, 0, 0, 0);
            }
            #pragma unroll
            for (int i = 0; i < 4; ++i) {
                float e0 = __builtin_amdgcn_exp2f(st0[i] * ESCALE);
                float e1 = __builtin_amdgcn_exp2f(st1[i] * ESCALE);
                if (maskc && (kb * 64 + g * 16 + quad * 4 + i >= vl)) { e0 = emaskval; e1 = emaskval; }
                lrun[0] += e0; lrun[1] += e1;
                pA[0][g][i] = (_Float16)e0;
                pA[1][g][i] = (_Float16)e1;
            }
        }

        // ---- O += P V : 4 kpos-tiles x 4 d-pairs ----
        #pragma unroll
        for (int g = 0; g < 4; ++g) {
            const _Float16* vc = vbase + (size_t)((kb * 4 + g) * 4) * 512;
            #pragma unroll
            for (int dp = 0; dp < 4; ++dp) {
                const f16x8 w  = *(const f16x8*)(vc + dp * 512);
                const f16x4 lo = __builtin_shufflevector(w, w, 0, 1, 2, 3);
                const f16x4 hi = __builtin_shufflevector(w, w, 4, 5, 6, 7);
                o[0][dp * 2]     = __builtin_amdgcn_mfma_f32_16x16x16f16(pA[0][g], lo, o[0][dp * 2],     0, 0, 0);
                o[0][dp * 2 + 1] = __builtin_amdgcn_mfma_f32_16x16x16f16(pA[0][g], hi, o[0][dp * 2 + 1], 0, 0, 0);
                o[1][dp * 2]     = __builtin_amdgcn_mfma_f32_16x16x16f16(pA[1][g], lo, o[1][dp * 2],     0, 0, 0);
                o[1][dp * 2 + 1] = __builtin_amdgcn_mfma_f32_16x16x16f16(pA[1][g], hi, o[1][dp * 2 + 1], 0, 0, 0);
            }
        }
    }

    // ---- split-K merge: wave w exports its OTHER half, keeps h = wv ----
    const int oh = 1 - wv;
    #pragma unroll
    for (int dt = 0; dt < 8; ++dt) Om[wv][dt][lane] = o[oh][dt];
    Lm[wv][lane] = lrun[oh];
    __syncthreads();
    f32x4 om[8];
    #pragma unroll
    for (int dt = 0; dt < 8; ++dt) om[dt] = o[wv][dt] + Om[oh][dt][lane];
    float L = lrun[wv] + Lm[oh][lane];

    // L[qrow=m16] total across quads, then per-row 1/L via shfl
    L += __shfl_xor(L, 16);
    L += __shfl_xor(L, 32);
    const size_t obase = ((size_t)b * LQ + q0 + wv * 16 + quad * 4) * DH + m16;
    #pragma unroll
    for (int r = 0; r < 4; ++r) {
        const float inv = 1.0f / __shfl(L, quad * 4 + r);
        #pragma unroll
        for (int dt = 0; dt < 8; ++dt)
            O[obase + (size_t)r * DH + dt * 16] = om[dt][r] * inv;
    }
}

extern "C" void kernel_launch(void* const* d_in, const int* in_sizes, int n_in,
                              void* d_out, int out_size, void* d_ws, size_t ws_size,
                              hipStream_t stream) {
    const float* Q  = (const float*)d_in[0];
    const float* K  = (const float*)d_in[1];
    const float* V  = (const float*)d_in[2];
    const int*   VL = (const int*)d_in[3];
    float* O = (float*)d_out;
    (void)in_sizes; (void)n_in; (void)out_size; (void)ws_size;

    unsigned short* Kb = (unsigned short*)d_ws;                      // 8 MB K fragments
    _Float16*       Vt = (_Float16*)(Kb + (size_t)B_N * 256 * 512);  // 8 MB V frag-pairs

    prep_kv<<<dim3(2048), dim3(256), 0, stream>>>(K, V, Kb, Vt);
    attn_fwd<<<dim3(B_N * (LQ / 32)), dim3(128), 0, stream>>>(Q, Kb, Vt, VL, O);
}

// Round 9
// 122.858 us; speedup vs baseline: 1.3162x; 1.1000x over previous
//
#include <hip/hip_runtime.h>

#define B_N 32
#define LQ  1024
#define LK  1024
#define DH  128

typedef __attribute__((ext_vector_type(4))) float    f32x4;
typedef __attribute__((ext_vector_type(8))) short    s16x8;
typedef __attribute__((ext_vector_type(4))) _Float16 f16x4;
typedef __attribute__((ext_vector_type(8))) _Float16 f16x8;

// fp32 -> bf16 round-to-nearest-even
__device__ inline unsigned short f2bf(float f) {
    union { float f; unsigned u; } c; c.f = f;
    unsigned u = c.u;
    u += 0x7fffu + ((u >> 16) & 1u);
    return (unsigned short)(u >> 16);
}

// logit2 = score * (1/sqrt(128)) * log2(e)
#define ESCALE 0.12751743f

// ---------------------------------------------------------------------------
// Prepass (unchanged from r8; fully coalesced via LDS tile transpose).
// blocks 0..1023: K tiles -> Kb bf16 fragments for QK^T (16x16x32):
//   frag w=b*256+tt*4+s: elem(lane,j) = K[b][tt*16+(lane&15)][s*32+(lane>>4)*8+j]
// blocks 1024..2047: V tiles -> Vt f16 fragment-PAIRS for PV (16x16x16):
//   pair v=(b*64+kg)*4+dp: elem(lane,i)   = V[b][kg*16+(lane>>4)*4+i][(2dp  )*16+(lane&15)]
//                          elem(lane,4+i) = V[b][kg*16+(lane>>4)*4+i][(2dp+1)*16+(lane&15)]
// ---------------------------------------------------------------------------
__global__ __launch_bounds__(256)
void prep_kv(const float* __restrict__ K, const float* __restrict__ V,
             unsigned short* __restrict__ Kb, _Float16* __restrict__ Vt)
{
    __shared__ float tl[32 * 132];
    const int tid  = threadIdx.x;
    const int lane = tid & 63;
    const int wv   = tid >> 6;
    const int n    = lane & 15;
    const int quad = lane >> 4;

    const bool isK = blockIdx.x < 1024;
    const int  t   = isK ? blockIdx.x : (blockIdx.x - 1024);
    const int  b   = t >> 5, kt = t & 31;

    const float4* src = (const float4*)((isK ? K : V) + ((size_t)b * LK + kt * 32) * DH);
    #pragma unroll
    for (int h = 0; h < 4; ++h) {
        const int idx = h * 256 + tid;
        const int row = idx >> 5, c4 = idx & 31;
        *(float4*)&tl[row * 132 + c4 * 4] = src[idx];
    }
    __syncthreads();

    if (isK) {
        union { s16x8 v; unsigned short u[8]; } t8;
        #pragma unroll
        for (int h = 0; h < 2; ++h) {
            const int f = wv * 2 + h;
            const int tt2 = f >> 2, s = f & 3;
            const float* p = &tl[(tt2 * 16 + n) * 132 + s * 32 + quad * 8];
            const float4 a = *(const float4*)p;
            const float4 c = *(const float4*)(p + 4);
            t8.u[0] = f2bf(a.x); t8.u[1] = f2bf(a.y); t8.u[2] = f2bf(a.z); t8.u[3] = f2bf(a.w);
            t8.u[4] = f2bf(c.x); t8.u[5] = f2bf(c.y); t8.u[6] = f2bf(c.z); t8.u[7] = f2bf(c.w);
            const int w = b * 256 + (kt * 2 + tt2) * 4 + s;
            *(s16x8*)(Kb + (size_t)w * 512 + lane * 8) = t8.v;
        }
    } else {
        #pragma unroll
        for (int h = 0; h < 2; ++h) {
            const int f  = wv * 2 + h;
            const int kg = f >> 2, dp = f & 3;
            f16x8 t8;
            #pragma unroll
            for (int i = 0; i < 4; ++i) {
                const float* row = &tl[(kg * 16 + quad * 4 + i) * 132 + dp * 32 + n];
                t8[i]     = (_Float16)row[0];
                t8[4 + i] = (_Float16)row[16];
            }
            const int v = (b * 64 + kt * 2 + kg) * 4 + dp;
            *(f16x8*)(Vt + (size_t)v * 512 + lane * 8) = t8;
        }
    }
}

// ---------------------------------------------------------------------------
// Attention: M=32 q-rows per wave, 2-wave blocks, split-K (wave w: chunks
// w, w+2, ...); fixed-max softmax makes partials additive -> one 16 KB LDS
// merge + one __syncthreads at the end.
// CRITICAL (r6/r7/r8 failure): the accumulator array must NEVER be indexed
// with a runtime value — o[oh]/o[wv]/lrun[oh] demoted o[2][8] to scratch
// (private memory) for its entire lifetime: ~65 MB/dispatch of scratch RMW
// (WRITE_SIZE 81-100 MB), VGPR_Count 92-128, insensitive to launch bounds.
// The epilogue below branches on the wave-uniform wv with CONSTANT indices.
// Transposed-S trick: S^T = K·Q^T C-layout (row=kpos=quad*4+i, col=qrow)
// == A-operand layout of 16x16x16 f16 MFMA -> exp2(S^T) feeds PV directly.
// ---------------------------------------------------------------------------
__global__ __launch_bounds__(128)
__attribute__((amdgpu_waves_per_eu(2, 2)))
void attn_fwd(const float* __restrict__ Q, const unsigned short* __restrict__ Kb,
              const _Float16* __restrict__ Vt, const int* __restrict__ VL,
              float* __restrict__ O)
{
    __shared__ f32x4 Om[2][8][64];
    __shared__ float Lm[2][64];

    const int tid  = threadIdx.x;
    const int lane = tid & 63;
    const int wv   = tid >> 6;
    const int quad = lane >> 4;
    const int m16  = lane & 15;

    // blockIdx = qg*32 + b: batch->XCD round-robin; ~2 MB Kb+Vt per XCD (L2).
    const int b  = blockIdx.x & 31;
    const int qg = blockIdx.x >> 5;
    const int q0 = qg * 32;

    const int vl = VL[b];
    const int nch = (vl > 0) ? ((vl + 63) >> 6) : 16;
    const float emaskval = (vl == 0) ? 1.0f : 0.0f;

    // Q fragments for 2 qrow-tiles (B-operand of transposed QK^T)
    s16x8 qf[2][4];
    #pragma unroll
    for (int h = 0; h < 2; ++h) {
        const float* qrow = Q + ((size_t)b * LQ + q0 + h * 16 + m16) * DH + quad * 8;
        #pragma unroll
        for (int s = 0; s < 4; ++s) {
            const float4 a = *(const float4*)(qrow + s * 32);
            const float4 c = *(const float4*)(qrow + s * 32 + 4);
            union { s16x8 v; unsigned short u[8]; } t;
            t.u[0] = f2bf(a.x); t.u[1] = f2bf(a.y); t.u[2] = f2bf(a.z); t.u[3] = f2bf(a.w);
            t.u[4] = f2bf(c.x); t.u[5] = f2bf(c.y); t.u[6] = f2bf(c.z); t.u[7] = f2bf(c.w);
            qf[h][s] = t.v;
        }
    }

    f32x4 o[2][8];
    #pragma unroll
    for (int h = 0; h < 2; ++h)
        #pragma unroll
        for (int dt = 0; dt < 8; ++dt) o[h][dt] = (f32x4){0.f, 0.f, 0.f, 0.f};
    float lrun[2] = {0.f, 0.f};

    const unsigned short* kbase = Kb + (size_t)b * (256 * 512) + lane * 8;
    const _Float16*       vbase = Vt + (size_t)b * (256 * 512) + lane * 8;

    for (int kb = wv; kb < nch; kb += 2) {
        const bool maskc = (kb * 64 + 64 > vl);
        f16x4 pA[2][4];

        // ---- S^T = K Q^T per 16-kpos tile g, softmaxed immediately ----
        #pragma unroll
        for (int g = 0; g < 4; ++g) {
            const unsigned short* kc = kbase + (size_t)((kb * 4 + g) * 4) * 512;
            f32x4 st0 = (f32x4){0.f, 0.f, 0.f, 0.f};
            f32x4 st1 = (f32x4){0.f, 0.f, 0.f, 0.f};
            #pragma unroll
            for (int s = 0; s < 4; ++s) {
                const s16x8 kf = *(const s16x8*)(kc + s * 512);
                st0 = __builtin_amdgcn_mfma_f32_16x16x32_bf16(kf, qf[0][s], st0, 0, 0, 0);
                st1 = __builtin_amdgcn_mfma_f32_16x16x32_bf16(kf, qf[1][s], st1, 0, 0, 0);
            }
            #pragma unroll
            for (int i = 0; i < 4; ++i) {
                float e0 = __builtin_amdgcn_exp2f(st0[i] * ESCALE);
                float e1 = __builtin_amdgcn_exp2f(st1[i] * ESCALE);
                if (maskc && (kb * 64 + g * 16 + quad * 4 + i >= vl)) { e0 = emaskval; e1 = emaskval; }
                lrun[0] += e0; lrun[1] += e1;
                pA[0][g][i] = (_Float16)e0;
                pA[1][g][i] = (_Float16)e1;
            }
        }

        // ---- O += P V : 4 kpos-tiles x 4 d-pairs ----
        #pragma unroll
        for (int g = 0; g < 4; ++g) {
            const _Float16* vc = vbase + (size_t)((kb * 4 + g) * 4) * 512;
            #pragma unroll
            for (int dp = 0; dp < 4; ++dp) {
                const f16x8 w  = *(const f16x8*)(vc + dp * 512);
                const f16x4 lo = __builtin_shufflevector(w, w, 0, 1, 2, 3);
                const f16x4 hi = __builtin_shufflevector(w, w, 4, 5, 6, 7);
                o[0][dp * 2]     = __builtin_amdgcn_mfma_f32_16x16x16f16(pA[0][g], lo, o[0][dp * 2],     0, 0, 0);
                o[0][dp * 2 + 1] = __builtin_amdgcn_mfma_f32_16x16x16f16(pA[0][g], hi, o[0][dp * 2 + 1], 0, 0, 0);
                o[1][dp * 2]     = __builtin_amdgcn_mfma_f32_16x16x16f16(pA[1][g], lo, o[1][dp * 2],     0, 0, 0);
                o[1][dp * 2 + 1] = __builtin_amdgcn_mfma_f32_16x16x16f16(pA[1][g], hi, o[1][dp * 2 + 1], 0, 0, 0);
            }
        }
    }

    // ---- split-K merge, CONSTANT register indices only (wv is wave-uniform,
    // so the branch is coherent; Om/Lm runtime indexing is fine — LDS is memory)
    f32x4 mine[8];
    float lmine;
    if (wv == 0) {
        #pragma unroll
        for (int dt = 0; dt < 8; ++dt) { Om[0][dt][lane] = o[1][dt]; mine[dt] = o[0][dt]; }
        Lm[0][lane] = lrun[1];
        lmine = lrun[0];
    } else {
        #pragma unroll
        for (int dt = 0; dt < 8; ++dt) { Om[1][dt][lane] = o[0][dt]; mine[dt] = o[1][dt]; }
        Lm[1][lane] = lrun[0];
        lmine = lrun[1];
    }
    __syncthreads();
    const int oh = 1 - wv;
    f32x4 om[8];
    #pragma unroll
    for (int dt = 0; dt < 8; ++dt) om[dt] = mine[dt] + Om[oh][dt][lane];
    float L = lmine + Lm[oh][lane];

    // L[qrow=m16] total across quads, then per-row 1/L via shfl
    L += __shfl_xor(L, 16);
    L += __shfl_xor(L, 32);
    const size_t obase = ((size_t)b * LQ + q0 + wv * 16 + quad * 4) * DH + m16;
    #pragma unroll
    for (int r = 0; r < 4; ++r) {
        const float inv = 1.0f / __shfl(L, quad * 4 + r);
        #pragma unroll
        for (int dt = 0; dt < 8; ++dt)
            O[obase + (size_t)r * DH + dt * 16] = om[dt][r] * inv;
    }
}

extern "C" void kernel_launch(void* const* d_in, const int* in_sizes, int n_in,
                              void* d_out, int out_size, void* d_ws, size_t ws_size,
                              hipStream_t stream) {
    const float* Q  = (const float*)d_in[0];
    const float* K  = (const float*)d_in[1];
    const float* V  = (const float*)d_in[2];
    const int*   VL = (const int*)d_in[3];
    float* O = (float*)d_out;
    (void)in_sizes; (void)n_in; (void)out_size; (void)ws_size;

    unsigned short* Kb = (unsigned short*)d_ws;                      // 8 MB K fragments
    _Float16*       Vt = (_Float16*)(Kb + (size_t)B_N * 256 * 512);  // 8 MB V frag-pairs

    prep_kv<<<dim3(2048), dim3(256), 0, stream>>>(K, V, Kb, Vt);
    attn_fwd<<<dim3(B_N * (LQ / 32)), dim3(128), 0, stream>>>(Q, Kb, Vt, VL, O);
}

// Round 10
// 118.453 us; speedup vs baseline: 1.3652x; 1.0372x over previous
//
#include <hip/hip_runtime.h>

#define B_N 32
#define LQ  1024
#define LK  1024
#define DH  128

typedef __attribute__((ext_vector_type(4))) float    f32x4;
typedef __attribute__((ext_vector_type(8))) short    s16x8;
typedef __attribute__((ext_vector_type(4))) _Float16 f16x4;
typedef __attribute__((ext_vector_type(8))) _Float16 f16x8;

// fp32 -> bf16 round-to-nearest-even
__device__ inline unsigned short f2bf(float f) {
    union { float f; unsigned u; } c; c.f = f;
    unsigned u = c.u;
    u += 0x7fffu + ((u >> 16) & 1u);
    return (unsigned short)(u >> 16);
}

// logit2 = score * (1/sqrt(128)) * log2(e)
#define ESCALE 0.12751743f

// ---------------------------------------------------------------------------
// Prepass with vl-aware skip (~46% of tiles never read by attn).
// blocks 0..1023: K tiles -> Kb bf16 fragments for QK^T (16x16x32). Needed
//   only for kt < 2*nch and vl>0 (vl==0: K values are masked everywhere).
// blocks 1024..2047: V tiles -> Vt f16 fragment-PAIRS for PV (16x16x16).
//   Needed for kt < 2*nch with nch=16 when vl==0 (P==1 -> O = mean(V)).
// Attn never touches fragments past nch chunks, so skipped tiles may hold
// harness poison (and for vl==0 the Kb poison feeds exp2 -> finite -> then
// overwritten by emaskval; no NaN path).
// ---------------------------------------------------------------------------
__global__ __launch_bounds__(256)
void prep_kv(const float* __restrict__ K, const float* __restrict__ V,
             const int* __restrict__ VL,
             unsigned short* __restrict__ Kb, _Float16* __restrict__ Vt)
{
    __shared__ float tl[32 * 132];
    const int tid  = threadIdx.x;
    const int lane = tid & 63;
    const int wv   = tid >> 6;
    const int n    = lane & 15;
    const int quad = lane >> 4;

    const bool isK = blockIdx.x < 1024;
    const int  t   = isK ? blockIdx.x : (blockIdx.x - 1024);
    const int  b   = t >> 5, kt = t & 31;

    const int vl = VL[b];
    if (isK) {
        if (vl <= 0 || kt >= 2 * ((vl + 63) >> 6)) return;   // block-uniform
    } else {
        const int nch = (vl > 0) ? ((vl + 63) >> 6) : 16;
        if (kt >= 2 * nch) return;                           // block-uniform
    }

    const float4* src = (const float4*)((isK ? K : V) + ((size_t)b * LK + kt * 32) * DH);
    #pragma unroll
    for (int h = 0; h < 4; ++h) {
        const int idx = h * 256 + tid;
        const int row = idx >> 5, c4 = idx & 31;
        *(float4*)&tl[row * 132 + c4 * 4] = src[idx];
    }
    __syncthreads();

    if (isK) {
        union { s16x8 v; unsigned short u[8]; } t8;
        #pragma unroll
        for (int h = 0; h < 2; ++h) {
            const int f = wv * 2 + h;
            const int tt2 = f >> 2, s = f & 3;
            const float* p = &tl[(tt2 * 16 + n) * 132 + s * 32 + quad * 8];
            const float4 a = *(const float4*)p;
            const float4 c = *(const float4*)(p + 4);
            t8.u[0] = f2bf(a.x); t8.u[1] = f2bf(a.y); t8.u[2] = f2bf(a.z); t8.u[3] = f2bf(a.w);
            t8.u[4] = f2bf(c.x); t8.u[5] = f2bf(c.y); t8.u[6] = f2bf(c.z); t8.u[7] = f2bf(c.w);
            const int w = b * 256 + (kt * 2 + tt2) * 4 + s;
            *(s16x8*)(Kb + (size_t)w * 512 + lane * 8) = t8.v;
        }
    } else {
        #pragma unroll
        for (int h = 0; h < 2; ++h) {
            const int f  = wv * 2 + h;
            const int kg = f >> 2, dp = f & 3;
            f16x8 t8;
            #pragma unroll
            for (int i = 0; i < 4; ++i) {
                const float* row = &tl[(kg * 16 + quad * 4 + i) * 132 + dp * 32 + n];
                t8[i]     = (_Float16)row[0];
                t8[4 + i] = (_Float16)row[16];
            }
            const int v = (b * 64 + kt * 2 + kg) * 4 + dp;
            *(f16x8*)(Vt + (size_t)v * 512 + lane * 8) = t8;
        }
    }
}

// ---------------------------------------------------------------------------
// Attention: M=32 q-rows per wave, 2-wave blocks, split-K (wave w: chunks
// w, w+2, ...); fixed-max softmax partials are additive -> one LDS merge +
// one __syncthreads at the end.
// Register rule (r6-r8 failure): NEVER index an accumulator array with a
// runtime value — o[oh] demoted o[][] to scratch (~65 MB/dispatch RMW).
// All register indices below are compile-time constants.
// Block swizzle: b's low 3 bits = blockIdx&7 (XCD affinity: 4 batches/XCD,
// ~1 MB working set in L2), b's top 2 bits mix in (idx>>3)+(idx>>8) so the
// stride-256 CU family {c, c+256, c+512, c+768} gets 4 DIFFERENT batches.
// Old qg*32+b mapping gave every CU 4 blocks of the SAME batch -> makespan
// = 2*max_b(nch) ~ 32 chunk-times vs ~17 mean. Bijective per 32-block group.
// Transposed-S trick: S^T = K·Q^T C-layout (row=kpos=quad*4+i, col=qrow)
// == A-operand layout of 16x16x16 f16 MFMA -> exp2(S^T) feeds PV directly.
// ---------------------------------------------------------------------------
__global__ __launch_bounds__(128)
__attribute__((amdgpu_waves_per_eu(2, 2)))
void attn_fwd(const float* __restrict__ Q, const unsigned short* __restrict__ Kb,
              const _Float16* __restrict__ Vt, const int* __restrict__ VL,
              float* __restrict__ O)
{
    __shared__ f32x4 Om[2][8][64];
    __shared__ float Lm[2][64];

    const int tid  = threadIdx.x;
    const int lane = tid & 63;
    const int wv   = tid >> 6;
    const int quad = lane >> 4;
    const int m16  = lane & 15;

    const int idx = blockIdx.x;
    const int qg  = idx >> 5;
    const int b   = (idx & 7) | ((((idx >> 3) + (idx >> 8)) & 3) << 3);
    const int q0  = qg * 32;

    const int vl = VL[b];
    const int nch = (vl > 0) ? ((vl + 63) >> 6) : 16;
    const float emaskval = (vl == 0) ? 1.0f : 0.0f;

    // Q fragments for 2 qrow-tiles (B-operand of transposed QK^T)
    s16x8 qf[2][4];
    #pragma unroll
    for (int h = 0; h < 2; ++h) {
        const float* qrow = Q + ((size_t)b * LQ + q0 + h * 16 + m16) * DH + quad * 8;
        #pragma unroll
        for (int s = 0; s < 4; ++s) {
            const float4 a = *(const float4*)(qrow + s * 32);
            const float4 c = *(const float4*)(qrow + s * 32 + 4);
            union { s16x8 v; unsigned short u[8]; } t;
            t.u[0] = f2bf(a.x); t.u[1] = f2bf(a.y); t.u[2] = f2bf(a.z); t.u[3] = f2bf(a.w);
            t.u[4] = f2bf(c.x); t.u[5] = f2bf(c.y); t.u[6] = f2bf(c.z); t.u[7] = f2bf(c.w);
            qf[h][s] = t.v;
        }
    }

    f32x4 o[2][8];
    #pragma unroll
    for (int h = 0; h < 2; ++h)
        #pragma unroll
        for (int dt = 0; dt < 8; ++dt) o[h][dt] = (f32x4){0.f, 0.f, 0.f, 0.f};
    float lrun[2] = {0.f, 0.f};

    const unsigned short* kbase = Kb + (size_t)b * (256 * 512) + lane * 8;
    const _Float16*       vbase = Vt + (size_t)b * (256 * 512) + lane * 8;

    for (int kb = wv; kb < nch; kb += 2) {
        const bool maskc = (kb * 64 + 64 > vl);
        f16x4 pA[2][4];

        // ---- S^T = K Q^T per 16-kpos tile g, softmaxed immediately ----
        #pragma unroll
        for (int g = 0; g < 4; ++g) {
            const unsigned short* kc = kbase + (size_t)((kb * 4 + g) * 4) * 512;
            f32x4 st0 = (f32x4){0.f, 0.f, 0.f, 0.f};
            f32x4 st1 = (f32x4){0.f, 0.f, 0.f, 0.f};
            #pragma unroll
            for (int s = 0; s < 4; ++s) {
                const s16x8 kf = *(const s16x8*)(kc + s * 512);
                st0 = __builtin_amdgcn_mfma_f32_16x16x32_bf16(kf, qf[0][s], st0, 0, 0, 0);
                st1 = __builtin_amdgcn_mfma_f32_16x16x32_bf16(kf, qf[1][s], st1, 0, 0, 0);
            }
            #pragma unroll
            for (int i = 0; i < 4; ++i) {
                float e0 = __builtin_amdgcn_exp2f(st0[i] * ESCALE);
                float e1 = __builtin_amdgcn_exp2f(st1[i] * ESCALE);
                if (maskc && (kb * 64 + g * 16 + quad * 4 + i >= vl)) { e0 = emaskval; e1 = emaskval; }
                lrun[0] += e0; lrun[1] += e1;
                pA[0][g][i] = (_Float16)e0;
                pA[1][g][i] = (_Float16)e1;
            }
        }

        // ---- O += P V : 4 kpos-tiles x 4 d-pairs ----
        #pragma unroll
        for (int g = 0; g < 4; ++g) {
            const _Float16* vc = vbase + (size_t)((kb * 4 + g) * 4) * 512;
            #pragma unroll
            for (int dp = 0; dp < 4; ++dp) {
                const f16x8 w  = *(const f16x8*)(vc + dp * 512);
                const f16x4 lo = __builtin_shufflevector(w, w, 0, 1, 2, 3);
                const f16x4 hi = __builtin_shufflevector(w, w, 4, 5, 6, 7);
                o[0][dp * 2]     = __builtin_amdgcn_mfma_f32_16x16x16f16(pA[0][g], lo, o[0][dp * 2],     0, 0, 0);
                o[0][dp * 2 + 1] = __builtin_amdgcn_mfma_f32_16x16x16f16(pA[0][g], hi, o[0][dp * 2 + 1], 0, 0, 0);
                o[1][dp * 2]     = __builtin_amdgcn_mfma_f32_16x16x16f16(pA[1][g], lo, o[1][dp * 2],     0, 0, 0);
                o[1][dp * 2 + 1] = __builtin_amdgcn_mfma_f32_16x16x16f16(pA[1][g], hi, o[1][dp * 2 + 1], 0, 0, 0);
            }
        }
    }

    // ---- split-K merge, CONSTANT register indices only ----
    f32x4 mine[8];
    float lmine;
    if (wv == 0) {
        #pragma unroll
        for (int dt = 0; dt < 8; ++dt) { Om[0][dt][lane] = o[1][dt]; mine[dt] = o[0][dt]; }
        Lm[0][lane] = lrun[1];
        lmine = lrun[0];
    } else {
        #pragma unroll
        for (int dt = 0; dt < 8; ++dt) { Om[1][dt][lane] = o[0][dt]; mine[dt] = o[1][dt]; }
        Lm[1][lane] = lrun[0];
        lmine = lrun[1];
    }
    __syncthreads();
    const int oh = 1 - wv;
    f32x4 om[8];
    #pragma unroll
    for (int dt = 0; dt < 8; ++dt) om[dt] = mine[dt] + Om[oh][dt][lane];
    float L = lmine + Lm[oh][lane];

    // L[qrow=m16] total across quads, then per-row 1/L via shfl
    L += __shfl_xor(L, 16);
    L += __shfl_xor(L, 32);
    const size_t obase = ((size_t)b * LQ + q0 + wv * 16 + quad * 4) * DH + m16;
    #pragma unroll
    for (int r = 0; r < 4; ++r) {
        const float inv = 1.0f / __shfl(L, quad * 4 + r);
        #pragma unroll
        for (int dt = 0; dt < 8; ++dt)
            O[obase + (size_t)r * DH + dt * 16] = om[dt][r] * inv;
    }
}

extern "C" void kernel_launch(void* const* d_in, const int* in_sizes, int n_in,
                              void* d_out, int out_size, void* d_ws, size_t ws_size,
                              hipStream_t stream) {
    const float* Q  = (const float*)d_in[0];
    const float* K  = (const float*)d_in[1];
    const float* V  = (const float*)d_in[2];
    const int*   VL = (const int*)d_in[3];
    float* O = (float*)d_out;
    (void)in_sizes; (void)n_in; (void)out_size; (void)ws_size;

    unsigned short* Kb = (unsigned short*)d_ws;                      // 8 MB K fragments
    _Float16*       Vt = (_Float16*)(Kb + (size_t)B_N * 256 * 512);  // 8 MB V frag-pairs

    prep_kv<<<dim3(2048), dim3(256), 0, stream>>>(K, V, VL, Kb, Vt);
    attn_fwd<<<dim3(B_N * (LQ / 32)), dim3(128), 0, stream>>>(Q, Kb, Vt, VL, O);
}